// Round 12
// baseline (225.012 us; speedup 1.0000x reference)
//
#include <hip/hip_runtime.h>
#include <hip/hip_bf16.h>

typedef short short8 __attribute__((ext_vector_type(8)));
typedef float f32x4 __attribute__((ext_vector_type(4)));
typedef int   i32x4 __attribute__((ext_vector_type(4)));
typedef unsigned short ushort_t;
typedef unsigned short ushort4v __attribute__((ext_vector_type(4)));

#define NBLK 2048
#define MFMA_BF16 __builtin_amdgcn_mfma_f32_16x16x32_bf16

__device__ __forceinline__ ushort_t f2bf(float f) {
    unsigned u = __float_as_uint(f);
    u += 0x7FFFu + ((u >> 16) & 1u);   // RTNE
    return (ushort_t)(u >> 16);
}
__device__ __forceinline__ void gll16(const void* g, void* l) {
    __builtin_amdgcn_global_load_lds(
        (const __attribute__((address_space(1))) unsigned*)g,
        (__attribute__((address_space(3))) unsigned*)l, 16, 0, 0);
}

// ================= prep =================
// xc tile tc = cb*64 + t64 (4 KB), fragment-ordered (R8-verified).
// wb block n (2 KB) fragment-ordered (R8-verified).
// gtab[g][128 phases][16]: [0..7]=slots ((n<<4)|(rig<<1)|1), [8]=col, [9]=cnt.
__global__ __launch_bounds__(256)
void prep_kernel(const float* __restrict__ x, const float* __restrict__ wblk,
                 const int* __restrict__ brows, const int* __restrict__ bcols,
                 ushort_t* __restrict__ xc, ushort_t* __restrict__ wb,
                 int* __restrict__ gtab, int* __restrict__ pcount) {
    __shared__ ushort_t pt[4][2048];
    __shared__ int k4[4][64];
    const int bid = blockIdx.x, tid = threadIdx.x;
    const int wv = tid >> 6, lane = tid & 63;

    if (bid < 1024) {
        // ---- x relayout+cvt (verbatim R8)
        const int tc = bid * 4 + wv;
        const int cb = tc >> 6, t64 = tc & 63;
        #pragma unroll
        for (int it = 0; it < 8; ++it) {
            int row = it * 8 + (lane >> 3);
            const float* src = x + (size_t)(t64 * 64 + row) * 2048 + cb * 32 + (lane & 7) * 4;
            float4 v = *reinterpret_cast<const float4*>(src);
            ushort4v o; o.x = f2bf(v.x); o.y = f2bf(v.y); o.z = f2bf(v.z); o.w = f2bf(v.w);
            int m = row >> 4, l15v = row & 15, hi = (lane & 7) >> 1;
            int cc = m * 64 + hi * 16 + l15v;
            *reinterpret_cast<ushort4v*>(&pt[wv][cc * 8 + (lane & 1) * 4]) = o;
        }
        #pragma unroll
        for (int rr = 0; rr < 4; ++rr) {
            i32x4 d = *reinterpret_cast<const i32x4*>(&pt[wv][(rr * 64 + lane) * 8]);
            *reinterpret_cast<i32x4*>(xc + (size_t)tc * 2048 + (rr * 64 + lane) * 8) = d;
        }
    } else if (bid < 2048) {
        // ---- w permute+cvt (verbatim R8)
        int d = (bid - 1024) * 256 + tid;
        int n = d >> 7, cc = d & 127;
        int nsub = cc >> 6, ln = cc & 63;
        int o_ = nsub * 16 + (ln & 15), kc = ln >> 4;
        const float* src = wblk + (size_t)n * 1024 + o_ * 32 + kc * 8;
        float4 v0 = *reinterpret_cast<const float4*>(src);
        float4 v1 = *reinterpret_cast<const float4*>(src + 4);
        short8 o8;
        o8[0] = f2bf(v0.x); o8[1] = f2bf(v0.y); o8[2] = f2bf(v0.z); o8[3] = f2bf(v0.w);
        o8[4] = f2bf(v1.x); o8[5] = f2bf(v1.y); o8[6] = f2bf(v1.z); o8[7] = f2bf(v1.w);
        reinterpret_cast<short8*>(wb)[d] = o8;
    } else {
        // ---- phase-table builder for rowgroup g; lane c owns column c; 4 waves scan quarters
        const int g = bid - 2048;
        const int c = lane;
        int* tg = gtab + g * 2048;   // 128 phases x 16 ints
        int k = 0;
        for (int i = wv * 512; i < wv * 512 + 512; ++i) {
            int rw = brows[i], cl = bcols[i];
            if (cl == c && (rw >> 3) == g) k++;
        }
        k4[wv][c] = k;
        __syncthreads();
        int kc = k4[0][c] + k4[1][c] + k4[2][c] + k4[3][c];
        int off = 0;
        for (int v = 0; v < 4; ++v) if (v < wv) off += k4[v][c];
        int nph = (kc + 7) >> 3;
        int sum = nph;
        for (int d = 1; d < 64; d <<= 1) {
            int t = __shfl_up(sum, d, 64);
            if (lane >= d) sum += t;
        }
        int base = sum - nph;
        int Pr = __shfl(sum, 63, 64);
        // pass 2: write slots (each wave writes its quarter's matches)
        int j = off;
        for (int i = wv * 512; i < wv * 512 + 512; ++i) {
            int rw = brows[i], cl = bcols[i];
            if (cl == c && (rw >> 3) == g) {
                int ph = base + (j >> 3), sl = j & 7;
                tg[ph * 16 + sl] = (i << 4) | ((rw & 7) << 1) | 1;
                j++;
            }
        }
        // col/cnt per phase (wave 0 only)
        if (wv == 0 && kc > 0) {
            for (int q = 0; q < nph; ++q) {
                tg[(base + q) * 16 + 8] = c;
                tg[(base + q) * 16 + 9] = (q == nph - 1) ? (kc - q * 8) : 8;
            }
        }
        // pads + count (one thread)
        if (wv == 0 && lane == 63) {
            int Pm = ((Pr + 2) / 3) * 3;
            for (int ph = Pr; ph < Pm + 2; ++ph) {
                tg[ph * 16 + 8] = 0;
                tg[ph * 16 + 9] = 0;
            }
            pcount[g] = Pm;
        }
    }
}

// ================= main kernel: column-phased, token-sliced waves =================
// 256 WGs x 512 thr (8 waves). WG = (g = wg&7 -> rows g*8..+8 [XCD-pinned W],
// slab = wg>>3 -> tokens slab*128..+128). Wave w: tokens (w>>1)*32..+32, outcols
// half (w&1); acc for ALL 8 rows. Per phase (one column): depth-3 LDS rings,
// counted vmcnt(3|1) (never 0 in loop), 1 barrier. Uniform work across waves.

#define BRD(dst, base, OFF) \
    asm volatile("ds_read_b128 %0, %1 offset:" #OFF : "=v"(dst) : "v"(base))

#define CASE_R(R, BV) case R: \
    acc##R##0 = MFMA_BF16(a0, BV, acc##R##0, 0, 0, 0); \
    acc##R##1 = MFMA_BF16(a1, BV, acc##R##1, 0, 0, 0); break;

#define DOSW(BV) switch (rig) { \
    CASE_R(0, BV) CASE_R(1, BV) CASE_R(2, BV) CASE_R(3, BV) \
    CASE_R(4, BV) CASE_R(5, BV) CASE_R(6, BV) CASE_R(7, BV) }

#define SLOT(S, BCUR, BNXT, NOFF, MS) \
    if ((S) < cnt) { \
        if ((S) + 1 < cnt) { BRD(BNXT, bbk, NOFF); \
            asm volatile("s_waitcnt lgkmcnt(1)" ::: "memory"); } \
        else { asm volatile("s_waitcnt lgkmcnt(0)" ::: "memory"); } \
        __builtin_amdgcn_sched_barrier(0); \
        int rig = (__builtin_amdgcn_readfirstlane(MS) >> 1) & 7; \
        DOSW(BCUR) \
    }

#define PHASE(RK, SK, BBK) { \
    const int pp = p + (RK); \
    int cnt  = __builtin_amdgcn_readfirstlane(ltab[pp * 16 + 9]); \
    short8 a0 = *reinterpret_cast<const short8*>(&aring[RK][awoff]); \
    short8 a1 = *reinterpret_cast<const short8*>(&aring[RK][awoff + 512]); \
    i32x4 m03 = *reinterpret_cast<const i32x4*>(&ltab[pp * 16]); \
    i32x4 m47 = *reinterpret_cast<const i32x4*>(&ltab[pp * 16 + 4]); \
    int col2 = ltab[(pp + 2) * 16 + 8]; \
    int cnt2 = __builtin_amdgcn_readfirstlane(ltab[(pp + 2) * 16 + 9]); \
    STAGE_A(col2, &aring[SK][0]); \
    if (w < cnt2) STAGE_B(ltab[(pp + 2) * 16 + w] >> 4, &bring[SK][0]); \
    unsigned bbk = (BBK); \
    short8 bA, bB; \
    if (cnt > 0) BRD(bA, bbk, 0); \
    SLOT(0, bA, bB, 2048,  m03[0]) \
    SLOT(1, bB, bA, 4096,  m03[1]) \
    SLOT(2, bA, bB, 6144,  m03[2]) \
    SLOT(3, bB, bA, 8192,  m03[3]) \
    SLOT(4, bA, bB, 10240, m47[0]) \
    SLOT(5, bB, bA, 12288, m47[1]) \
    SLOT(6, bA, bB, 14336, m47[2]) \
    SLOT(7, bB, bA, 0,     m47[3]) \
    if (w < cnt2) { asm volatile("s_waitcnt vmcnt(3)" ::: "memory"); } \
    else          { asm volatile("s_waitcnt vmcnt(1)" ::: "memory"); } \
    __builtin_amdgcn_s_barrier(); \
}

#define OUTR(R) { \
    const int oc = (g * 8 + (R)) * 32 + (w & 1) * 16 + l15; \
    const int tb = slab * 128 + (w >> 1) * 32 + hi * 4; \
    out[(size_t)(tb + 0) * 2048 + oc]  = acc##R##0[0]; \
    out[(size_t)(tb + 1) * 2048 + oc]  = acc##R##0[1]; \
    out[(size_t)(tb + 2) * 2048 + oc]  = acc##R##0[2]; \
    out[(size_t)(tb + 3) * 2048 + oc]  = acc##R##0[3]; \
    out[(size_t)(tb + 16) * 2048 + oc] = acc##R##1[0]; \
    out[(size_t)(tb + 17) * 2048 + oc] = acc##R##1[1]; \
    out[(size_t)(tb + 18) * 2048 + oc] = acc##R##1[2]; \
    out[(size_t)(tb + 19) * 2048 + oc] = acc##R##1[3]; \
}

__global__ __launch_bounds__(512)
void bsl_mfma_kernel(const ushort_t* __restrict__ xc,
                     const ushort_t* __restrict__ wb,
                     const int* __restrict__ gtab,
                     const int* __restrict__ pcount,
                     float* __restrict__ out) {
    __shared__ ushort_t aring[3][4096];   // 3 x 8 KB A-panel ring
    __shared__ ushort_t bring[3][8192];   // 3 x 16 KB (8 slots x 2 KB) B ring
    __shared__ int      ltab[2048];       // 128 phases x 16 ints

    const int wg = blockIdx.x;
    const int g = wg & 7, slab = wg >> 3;
    const int tid = threadIdx.x, w = tid >> 6, lane = tid & 63;
    const int l15 = lane & 15, hi = lane >> 4;

    const int* gt = gtab + g * 2048;
    for (int i = tid; i < 2048; i += 512) ltab[i] = gt[i];
    const int Pm = pcount[g];
    __syncthreads();

    f32x4 acc00 = {0,0,0,0}, acc01 = {0,0,0,0}, acc10 = {0,0,0,0}, acc11 = {0,0,0,0};
    f32x4 acc20 = {0,0,0,0}, acc21 = {0,0,0,0}, acc30 = {0,0,0,0}, acc31 = {0,0,0,0};
    f32x4 acc40 = {0,0,0,0}, acc41 = {0,0,0,0}, acc50 = {0,0,0,0}, acc51 = {0,0,0,0};
    f32x4 acc60 = {0,0,0,0}, acc61 = {0,0,0,0}, acc70 = {0,0,0,0}, acc71 = {0,0,0,0};

    auto STAGE_A = [&](int col, ushort_t* dst) {
        const ushort_t* src = xc + (size_t)(col * 64 + 2 * slab + (w >> 2)) * 2048
                                 + (w & 3) * 512 + lane * 8;
        gll16(src, dst + w * 512);
    };
    auto STAGE_B = [&](int n, ushort_t* dst) {
        const ushort_t* src = wb + (size_t)n * 1024 + lane * 8;
        gll16(src,       dst + w * 1024);
        gll16(src + 512, dst + w * 1024 + 512);
    };

    // prologue: stage phases 0,1 into rings 0,1
    {
        int cnt0 = __builtin_amdgcn_readfirstlane(ltab[9]);
        int col0 = ltab[8];
        int cnt1 = __builtin_amdgcn_readfirstlane(ltab[16 + 9]);
        int col1 = ltab[16 + 8];
        STAGE_A(col0, &aring[0][0]);
        if (w < cnt0) STAGE_B(ltab[w] >> 4, &bring[0][0]);
        STAGE_A(col1, &aring[1][0]);
        if (w < cnt1) STAGE_B(ltab[16 + w] >> 4, &bring[1][0]);
        if (w < cnt1) { asm volatile("s_waitcnt vmcnt(3)" ::: "memory"); }
        else          { asm volatile("s_waitcnt vmcnt(1)" ::: "memory"); }
        __builtin_amdgcn_s_barrier();
    }

    const int awoff = (w >> 1) * 1024 + lane * 8;   // ushort index into aring slot
    unsigned bb0 = (unsigned)(size_t)&bring[0][0] + (w & 1) * 1024 + lane * 16;
    unsigned bb1 = (unsigned)(size_t)&bring[1][0] + (w & 1) * 1024 + lane * 16;
    unsigned bb2 = (unsigned)(size_t)&bring[2][0] + (w & 1) * 1024 + lane * 16;

    for (int p = 0; p < Pm; p += 3) {
        PHASE(0, 2, bb0)
        PHASE(1, 0, bb1)
        PHASE(2, 1, bb2)
    }
    asm volatile("s_waitcnt vmcnt(0) lgkmcnt(0)" ::: "memory");

    OUTR(0) OUTR(1) OUTR(2) OUTR(3) OUTR(4) OUTR(5) OUTR(6) OUTR(7)
}

extern "C" void kernel_launch(void* const* d_in, const int* in_sizes, int n_in,
                              void* d_out, int out_size, void* d_ws, size_t ws_size,
                              hipStream_t stream) {
    const float* x     = (const float*)d_in[0];
    const float* wblk  = (const float*)d_in[1];
    const int*   brows = (const int*)d_in[2];
    const int*   bcols = (const int*)d_in[3];
    float*       out   = (float*)d_out;

    char* ws = (char*)d_ws;
    ushort_t* xc     = (ushort_t*)(ws);                    // 16,777,216 B
    ushort_t* wb     = (ushort_t*)(ws + 16777216);         //  4,194,304 B
    int*      gtab   = (int*)(ws + 20971520);              //     65,536 B (8 x 128 x 16)
    int*      pcount = (int*)(ws + 21037056);              //         32 B

    // 1024 (x tiles) + 1024 (w cvt) + 8 (table builders)
    prep_kernel<<<2056, 256, 0, stream>>>(x, wblk, brows, bcols, xc, wb, gtab, pcount);
    bsl_mfma_kernel<<<256, 512, 0, stream>>>(xc, wb, gtab, pcount, out);
}

// Round 13
// 62.600 us; speedup vs baseline: 3.5945x; 3.5945x over previous
//
#include <hip/hip_runtime.h>
#include <hip/hip_bf16.h>

typedef short short8 __attribute__((ext_vector_type(8)));
typedef float f32x4 __attribute__((ext_vector_type(4)));
typedef int   i32x4 __attribute__((ext_vector_type(4)));
typedef unsigned short ushort_t;
typedef unsigned short ushort4v __attribute__((ext_vector_type(4)));

#define NBLK   2048
#define ROWCAP 96
#define ZENT   (NBLK << 6)   // pad entry -> zero weight block, col 0
#define MFMA_BF16 __builtin_amdgcn_mfma_f32_16x16x32_bf16

__device__ __forceinline__ ushort_t f2bf(float f) {
    unsigned u = __float_as_uint(f);
    u += 0x7FFFu + ((u >> 16) & 1u);   // RTNE
    return (ushort_t)(u >> 16);
}
__device__ __forceinline__ void gll16(const void* g, void* l) {
    __builtin_amdgcn_global_load_lds(
        (const __attribute__((address_space(1))) unsigned*)g,
        (__attribute__((address_space(3))) unsigned*)l, 16, 0, 0);
}

// ================= prep (verbatim R8, passed) =================
__global__ __launch_bounds__(256)
void prep_kernel(const float* __restrict__ x, const float* __restrict__ wblk,
                 const int* __restrict__ brows, const int* __restrict__ bcols,
                 ushort_t* __restrict__ xc, ushort_t* __restrict__ wb,
                 int* __restrict__ bucket, int* __restrict__ bcnt) {
    __shared__ ushort_t pt[4][2048];
    const int bid = blockIdx.x, tid = threadIdx.x;
    const int wv = tid >> 6, lane = tid & 63;

    if (bid < 1024) {
        const int tc = bid * 4 + wv;
        const int cb = tc >> 6, t64 = tc & 63;
        #pragma unroll
        for (int it = 0; it < 8; ++it) {
            int row = it * 8 + (lane >> 3);
            const float* src = x + (size_t)(t64 * 64 + row) * 2048 + cb * 32 + (lane & 7) * 4;
            float4 v = *reinterpret_cast<const float4*>(src);
            ushort4v o; o.x = f2bf(v.x); o.y = f2bf(v.y); o.z = f2bf(v.z); o.w = f2bf(v.w);
            int m = row >> 4, l15v = row & 15, hi = (lane & 7) >> 1;
            int cc = m * 64 + hi * 16 + l15v;
            *reinterpret_cast<ushort4v*>(&pt[wv][cc * 8 + (lane & 1) * 4]) = o;
        }
        #pragma unroll
        for (int rr = 0; rr < 4; ++rr) {
            i32x4 d = *reinterpret_cast<const i32x4*>(&pt[wv][(rr * 64 + lane) * 8]);
            *reinterpret_cast<i32x4*>(xc + (size_t)tc * 2048 + (rr * 64 + lane) * 8) = d;
        }
    } else if (bid < 2048) {
        int d = (bid - 1024) * 256 + tid;
        int n = d >> 7, cc = d & 127;
        int nsub = cc >> 6, ln = cc & 63;
        int o_ = nsub * 16 + (ln & 15), kc = ln >> 4;
        const float* src = wblk + (size_t)n * 1024 + o_ * 32 + kc * 8;
        float4 v0 = *reinterpret_cast<const float4*>(src);
        float4 v1 = *reinterpret_cast<const float4*>(src + 4);
        short8 o8;
        o8[0] = f2bf(v0.x); o8[1] = f2bf(v0.y); o8[2] = f2bf(v0.z); o8[3] = f2bf(v0.w);
        o8[4] = f2bf(v1.x); o8[5] = f2bf(v1.y); o8[6] = f2bf(v1.z); o8[7] = f2bf(v1.w);
        reinterpret_cast<short8*>(wb)[d] = o8;
    } else if (bid == 2048) {
        if (tid < 128) {
            short8 z = (short8){0,0,0,0,0,0,0,0};
            reinterpret_cast<short8*>(wb + (size_t)NBLK * 1024)[tid] = z;
        }
    } else {
        const int r = (bid - 2049) * 4 + wv;
        const int per = NBLK / 64;
        const int base = lane * per;
        int cnt = 0;
        for (int k = 0; k < per; ++k) cnt += (brows[base + k] == r) ? 1 : 0;
        int sum = cnt;
        for (int d = 1; d < 64; d <<= 1) {
            int v = __shfl_up(sum, d, 64);
            if (lane >= d) sum += v;
        }
        int off = sum - cnt;
        for (int k = 0; k < per; ++k) {
            int n = base + k;
            if (brows[n] == r) bucket[r * ROWCAP + (off++)] = (n << 6) | bcols[n];
        }
        int total = __shfl(sum, 63, 64);
        if (lane < 8) bucket[r * ROWCAP + total + lane] = ZENT;
        if (lane == 0) bcnt[r] = total;
    }
}

// ================= main kernel (R8 chassis + distance-3 B-in-registers) =================
// 1024 WGs x 128 thr (2 waves). Wave job = (row r, 128-token slab), R8 map.
// A: per-wave private depth-3 LDS ring (8 KB slots), gll16, distance 2 (L2-covered).
// B: registers, distance 3 (~600+ cyc — covers L3 latency, the R8 stall source).
// Per subiter: 8 A-gll16 + 2 B-loads = 10 vm ops; counted vmcnt(10); no barriers.
#define DSR(d, a, o) asm volatile("ds_read_b128 %0, %1 offset:" #o : "=v"(d) : "v"(a))

#define SUBITER(FB, SPX, EA, BC0, BC1, EB) do {                                \
    short8 a0,a1,a2,a3,a4,a5,a6,a7;                                            \
    asm volatile("s_waitcnt vmcnt(10)" ::: "memory");                          \
    __builtin_amdgcn_sched_barrier(0);                                         \
    DSR(a0, FB, 0);    DSR(a1, FB, 1024); DSR(a2, FB, 2048); DSR(a3, FB, 3072);\
    DSR(a4, FB, 4096); DSR(a5, FB, 5120); DSR(a6, FB, 6144); DSR(a7, FB, 7168);\
    STAGE(SPX, EA);                                                            \
    asm volatile("ds_read_b32 %0, %1" : "=v"(EA) : "v"(laddr) : "memory");     \
    laddr += 4;                                                                \
    asm volatile("s_waitcnt lgkmcnt(0)" ::: "memory");                         \
    __builtin_amdgcn_sched_barrier(0);                                         \
    __builtin_amdgcn_s_setprio(1);                                             \
    acc[0][0] = MFMA_BF16(a0, BC0, acc[0][0], 0,0,0);                          \
    acc[0][1] = MFMA_BF16(a0, BC1, acc[0][1], 0,0,0);                          \
    acc[1][0] = MFMA_BF16(a1, BC0, acc[1][0], 0,0,0);                          \
    acc[1][1] = MFMA_BF16(a1, BC1, acc[1][1], 0,0,0);                          \
    acc[2][0] = MFMA_BF16(a2, BC0, acc[2][0], 0,0,0);                          \
    acc[2][1] = MFMA_BF16(a2, BC1, acc[2][1], 0,0,0);                          \
    acc[3][0] = MFMA_BF16(a3, BC0, acc[3][0], 0,0,0);                          \
    acc[3][1] = MFMA_BF16(a3, BC1, acc[3][1], 0,0,0);                          \
    acc[4][0] = MFMA_BF16(a4, BC0, acc[4][0], 0,0,0);                          \
    acc[4][1] = MFMA_BF16(a4, BC1, acc[4][1], 0,0,0);                          \
    acc[5][0] = MFMA_BF16(a5, BC0, acc[5][0], 0,0,0);                          \
    acc[5][1] = MFMA_BF16(a5, BC1, acc[5][1], 0,0,0);                          \
    acc[6][0] = MFMA_BF16(a6, BC0, acc[6][0], 0,0,0);                          \
    acc[6][1] = MFMA_BF16(a6, BC1, acc[6][1], 0,0,0);                          \
    acc[7][0] = MFMA_BF16(a7, BC0, acc[7][0], 0,0,0);                          \
    acc[7][1] = MFMA_BF16(a7, BC1, acc[7][1], 0,0,0);                          \
    __builtin_amdgcn_s_setprio(0);                                             \
    {   /* reload this B set for entry (j+3): consumed above, WAR-safe */      \
        int eu = __builtin_amdgcn_readfirstlane(EB);                           \
        const ushort_t* bp = wb + ((size_t)(unsigned)(eu >> 6) << 10) + lane * 8; \
        BC0 = *reinterpret_cast<const short8*>(bp);                            \
        BC1 = *reinterpret_cast<const short8*>(bp + 512);                      \
    }                                                                          \
    __builtin_amdgcn_sched_barrier(0);                                         \
} while (0)

__global__ __launch_bounds__(128)
void bsl_mfma_kernel(const ushort_t* __restrict__ xc,
                     const ushort_t* __restrict__ wb,
                     const int* __restrict__ bucket,
                     const int* __restrict__ bcnt,
                     float* __restrict__ out) {
    __shared__ ushort_t ring[2][3][4096];   // per wave: 3 x 8 KB A slots (48 KB)
    __shared__ int      llist[2][96];

    const int wg   = blockIdx.x;            // [0,1024)
    const int q    = wg & 7;                // XCD residue -> slab group (R8 map)
    const int i    = wg >> 3;               // [0,128)
    const int slab = q * 4 + (i & 3);       // [0,32): 128-token slab, L2-pinned A
    const int tid  = threadIdx.x;
    const int wv   = tid >> 6, lane = tid & 63;
    const int r    = (i >> 2) * 2 + wv;     // [0,64): output row-block
    const int l15  = lane & 15, hi = lane >> 4;
    const int tok0 = slab * 128;

    const int cnt = bcnt[r];

    // ---- list -> LDS (lgkm path; keeps vmcnt clean in the loop)
    int lv = 0;
    if (lane < ROWCAP) lv = bucket[r * ROWCAP + lane];
    asm volatile("s_waitcnt vmcnt(0)" ::: "memory");
    if (lane < ROWCAP) llist[wv][lane] = lv;
    int e0 = llist[wv][0], e1 = llist[wv][1];
    int ea = llist[wv][2], eb = llist[wv][3], ec = llist[wv][4];

    const ushort_t* xsrc = xc + lane * 8;
    ushort_t* sp0 = &ring[wv][0][0];
    ushort_t* sp1 = &ring[wv][1][0];
    ushort_t* sp2 = &ring[wv][2][0];

    auto STAGE = [&](ushort_t* sp, int e) {
        int eu = __builtin_amdgcn_readfirstlane(e);
        const ushort_t* as = xsrc + ((size_t)((eu & 63) * 64 + 2 * slab) << 11);
        #pragma unroll
        for (int t = 0; t < 8; ++t) gll16(as + t * 512, sp + t * 512);
    };

    f32x4 acc[8][2];
    #pragma unroll
    for (int m = 0; m < 8; ++m) {
        acc[m][0] = (f32x4){0.f, 0.f, 0.f, 0.f};
        acc[m][1] = (f32x4){0.f, 0.f, 0.f, 0.f};
    }

    unsigned fb0 = (unsigned)(size_t)&ring[wv][0][0] + lane * 16;
    unsigned fb1 = fb0 + 8192;
    unsigned fb2 = fb0 + 16384;
    unsigned laddr = (unsigned)(size_t)&llist[wv][0] + 5 * 4;

    // prologue: stage A(0),A(1); preload B(0),B(1),B(2) into the 3 reg sets
    STAGE(sp0, e0);
    STAGE(sp1, e1);
    short8 B00, B01, B10, B11, B20, B21;
    {
        int eu = __builtin_amdgcn_readfirstlane(e0);
        const ushort_t* bp = wb + ((size_t)(unsigned)(eu >> 6) << 10) + lane * 8;
        B00 = *reinterpret_cast<const short8*>(bp);
        B01 = *reinterpret_cast<const short8*>(bp + 512);
        eu = __builtin_amdgcn_readfirstlane(e1);
        bp = wb + ((size_t)(unsigned)(eu >> 6) << 10) + lane * 8;
        B10 = *reinterpret_cast<const short8*>(bp);
        B11 = *reinterpret_cast<const short8*>(bp + 512);
        eu = __builtin_amdgcn_readfirstlane(ea);
        bp = wb + ((size_t)(unsigned)(eu >> 6) << 10) + lane * 8;
        B20 = *reinterpret_cast<const short8*>(bp);
        B21 = *reinterpret_cast<const short8*>(bp + 512);
    }
    asm volatile("s_waitcnt vmcnt(0)" ::: "memory");
    __builtin_amdgcn_sched_barrier(0);

    const int cnt3 = ((cnt + 2) / 3) * 3;   // pads are zero-W blocks
    for (int j = 0; j < cnt3; j += 3) {
        SUBITER(fb0, sp2, ea, B00, B01, eb);  // compute0: A ring0 + Bset0; stage A(j+2); load B(j+3)->set0
        SUBITER(fb1, sp0, eb, B10, B11, ec);  // compute1: stage A(j+3); load B(j+4)->set1
        SUBITER(fb2, sp1, ec, B20, B21, ea);  // compute2: stage A(j+4); load B(j+5)->set2
    }
    asm volatile("s_waitcnt vmcnt(0) lgkmcnt(0)" ::: "memory");

    // C/D layout: col = lane&15, row = (lane>>4)*4 + reg  [HW-verified]
    const int outc = r * 32 + l15;
    #pragma unroll
    for (int m = 0; m < 8; ++m) {
        #pragma unroll
        for (int ns = 0; ns < 2; ++ns) {
            #pragma unroll
            for (int reg = 0; reg < 4; ++reg) {
                int token = tok0 + m * 16 + hi * 4 + reg;
                out[(size_t)token * 2048 + outc + ns * 16] = acc[m][ns][reg];
            }
        }
    }
}

extern "C" void kernel_launch(void* const* d_in, const int* in_sizes, int n_in,
                              void* d_out, int out_size, void* d_ws, size_t ws_size,
                              hipStream_t stream) {
    const float* x     = (const float*)d_in[0];
    const float* wblk  = (const float*)d_in[1];
    const int*   brows = (const int*)d_in[2];
    const int*   bcols = (const int*)d_in[3];
    float*       out   = (float*)d_out;

    char* ws = (char*)d_ws;
    ushort_t* xc     = (ushort_t*)(ws);                    // 16,777,216 B
    ushort_t* wb     = (ushort_t*)(ws + 16777216);         //  4,196,352 B (2049 blocks)
    int*      bucket = (int*)(ws + 20973568);              //     24,576 B (64 x 96)
    int*      bcnt   = (int*)(ws + 20998144);              //        256 B

    // 1024 (x tiles) + 1024 (w cvt) + 1 (zero blk) + 16 (bucketize)
    prep_kernel<<<2065, 256, 0, stream>>>(x, wblk, brows, bcols, xc, wb, bucket, bcnt);
    bsl_mfma_kernel<<<1024, 128, 0, stream>>>(xc, wb, bucket, bcnt, out);
}